// Round 2
// baseline (1011.209 us; speedup 1.0000x reference)
//
#include <hip/hip_runtime.h>

#define VN_EPS 1e-12f
#define CHUNK_FACES 4096

// XCC (XCD) id of the CU this wave runs on. Verified returning 0-7 on MI355X.
// Symbolic hwreg name -> assembler error (not silent garbage) if unsupported.
__device__ __forceinline__ unsigned get_xcc_id() {
    unsigned x;
    asm volatile("s_getreg_b32 %0, hwreg(HW_REG_XCC_ID)" : "=s"(x));
    return x & 7u;
}

// Near atomic: performed in the issuing XCD's L2 (no sc1 write-through).
// Atomic w.r.t. every CU on the same XCD, which is all we need once the
// output is sharded so each vertex is touched by exactly one XCD.
__device__ __forceinline__ void near_atomic_add(float* p, float v) {
    __hip_atomic_fetch_add(p, v, __ATOMIC_RELAXED, __HIP_MEMORY_SCOPE_WORKGROUP);
}

__device__ __forceinline__ void face_normal_from_verts(
    const float* __restrict__ v, int i0, int i1, int i2,
    float& nx, float& ny, float& nz) {
    float v0x = v[3 * i0 + 0], v0y = v[3 * i0 + 1], v0z = v[3 * i0 + 2];
    float v1x = v[3 * i1 + 0], v1y = v[3 * i1 + 1], v1z = v[3 * i1 + 2];
    float v2x = v[3 * i2 + 0], v2y = v[3 * i2 + 1], v2z = v[3 * i2 + 2];

    float e0x = v1x - v0x, e0y = v1y - v0y, e0z = v1z - v0z;
    float e1x = v2x - v1x, e1y = v2y - v1y, e1z = v2z - v1z;
    float e2x = v0x - v2x, e2y = v0y - v2y, e2z = v0z - v2z;

    // cross(e0,e1) + cross(e1,e2) + cross(e2,e0) — matches reference numerics.
    nx = (e0y * e1z - e0z * e1y) + (e1y * e2z - e1z * e2y) + (e2y * e0z - e2z * e0y);
    ny = (e0z * e1x - e0x * e1z) + (e1z * e2x - e1x * e2z) + (e2z * e0x - e2x * e0z);
    nz = (e0x * e1y - e0y * e1x) + (e1x * e2y - e1y * e2x) + (e2x * e0y - e2y * e0x);
}

// ---- Stage A: face normals, computed once, coalesced write to d_ws. ----
__global__ void vn_face_normals(const float* __restrict__ v,
                                const int* __restrict__ faces,
                                float* __restrict__ fn,
                                int n_faces) {
    int f = blockIdx.x * blockDim.x + threadIdx.x;
    if (f >= n_faces) return;
    int i0 = faces[3 * f + 0];
    int i1 = faces[3 * f + 1];
    int i2 = faces[3 * f + 2];
    float nx, ny, nz;
    face_normal_from_verts(v, i0, i1, i2, nx, ny, nz);
    fn[3 * f + 0] = nx;
    fn[3 * f + 1] = ny;
    fn[3 * f + 2] = nz;
}

// ---- Stage B: sharded scatter. Each XCD owns vertex range
// [xcc*vps, (xcc+1)*vps); blocks pull face-chunks from their XCD's queue so
// every face is processed exactly once per shard regardless of block->XCD
// placement. Atomics are L2-local (near), target region 1.5 MB -> resident. ----
__global__ void vn_scatter_fn(const int* __restrict__ faces,
                              const float* __restrict__ fn,
                              float* __restrict__ vn,
                              int* __restrict__ counters,
                              int n_faces, int n_chunks, int vps) {
    unsigned xcc = get_xcc_id();
    int lo = (int)xcc * vps;
    int hi = lo + vps;
    __shared__ int s_chunk;
    for (;;) {
        if (threadIdx.x == 0) s_chunk = atomicAdd(&counters[xcc], 1);
        __syncthreads();
        int c = s_chunk;
        __syncthreads();
        if (c >= n_chunks) return;
        int base = c * CHUNK_FACES;
        int end = base + CHUNK_FACES;
        if (end > n_faces) end = n_faces;
        for (int f = base + (int)threadIdx.x; f < end; f += (int)blockDim.x) {
            int i0 = faces[3 * f + 0];
            int i1 = faces[3 * f + 1];
            int i2 = faces[3 * f + 2];
            bool a0 = (i0 >= lo) & (i0 < hi);
            bool a1 = (i1 >= lo) & (i1 < hi);
            bool a2 = (i2 >= lo) & (i2 < hi);
            if (a0 | a1 | a2) {
                float nx = fn[3 * f + 0];
                float ny = fn[3 * f + 1];
                float nz = fn[3 * f + 2];
                if (a0) {
                    near_atomic_add(&vn[3 * i0 + 0], nx);
                    near_atomic_add(&vn[3 * i0 + 1], ny);
                    near_atomic_add(&vn[3 * i0 + 2], nz);
                }
                if (a1) {
                    near_atomic_add(&vn[3 * i1 + 0], nx);
                    near_atomic_add(&vn[3 * i1 + 1], ny);
                    near_atomic_add(&vn[3 * i1 + 2], nz);
                }
                if (a2) {
                    near_atomic_add(&vn[3 * i2 + 0], nx);
                    near_atomic_add(&vn[3 * i2 + 1], ny);
                    near_atomic_add(&vn[3 * i2 + 2], nz);
                }
            }
        }
    }
}

// ---- Tier-2: same sharded scatter but recompute normals inline (no fn ws). ----
__global__ void vn_scatter_recompute(const float* __restrict__ v,
                                     const int* __restrict__ faces,
                                     float* __restrict__ vn,
                                     int* __restrict__ counters,
                                     int n_faces, int n_chunks, int vps) {
    unsigned xcc = get_xcc_id();
    int lo = (int)xcc * vps;
    int hi = lo + vps;
    __shared__ int s_chunk;
    for (;;) {
        if (threadIdx.x == 0) s_chunk = atomicAdd(&counters[xcc], 1);
        __syncthreads();
        int c = s_chunk;
        __syncthreads();
        if (c >= n_chunks) return;
        int base = c * CHUNK_FACES;
        int end = base + CHUNK_FACES;
        if (end > n_faces) end = n_faces;
        for (int f = base + (int)threadIdx.x; f < end; f += (int)blockDim.x) {
            int i0 = faces[3 * f + 0];
            int i1 = faces[3 * f + 1];
            int i2 = faces[3 * f + 2];
            bool a0 = (i0 >= lo) & (i0 < hi);
            bool a1 = (i1 >= lo) & (i1 < hi);
            bool a2 = (i2 >= lo) & (i2 < hi);
            if (a0 | a1 | a2) {
                float nx, ny, nz;
                face_normal_from_verts(v, i0, i1, i2, nx, ny, nz);
                if (a0) {
                    near_atomic_add(&vn[3 * i0 + 0], nx);
                    near_atomic_add(&vn[3 * i0 + 1], ny);
                    near_atomic_add(&vn[3 * i0 + 2], nz);
                }
                if (a1) {
                    near_atomic_add(&vn[3 * i1 + 0], nx);
                    near_atomic_add(&vn[3 * i1 + 1], ny);
                    near_atomic_add(&vn[3 * i1 + 2], nz);
                }
                if (a2) {
                    near_atomic_add(&vn[3 * i2 + 0], nx);
                    near_atomic_add(&vn[3 * i2 + 1], ny);
                    near_atomic_add(&vn[3 * i2 + 2], nz);
                }
            }
        }
    }
}

// ---- Tier-3 fallback: original device-scope scatter (only if ws is tiny). ----
__global__ void vn_face_scatter(const float* __restrict__ v,
                                const int* __restrict__ faces,
                                float* __restrict__ vn,
                                int n_faces) {
    int f = blockIdx.x * blockDim.x + threadIdx.x;
    if (f >= n_faces) return;
    int i0 = faces[3 * f + 0];
    int i1 = faces[3 * f + 1];
    int i2 = faces[3 * f + 2];
    float nx, ny, nz;
    face_normal_from_verts(v, i0, i1, i2, nx, ny, nz);
    atomicAdd(&vn[3 * i0 + 0], nx);
    atomicAdd(&vn[3 * i0 + 1], ny);
    atomicAdd(&vn[3 * i0 + 2], nz);
    atomicAdd(&vn[3 * i1 + 0], nx);
    atomicAdd(&vn[3 * i1 + 1], ny);
    atomicAdd(&vn[3 * i1 + 2], nz);
    atomicAdd(&vn[3 * i2 + 0], nx);
    atomicAdd(&vn[3 * i2 + 1], ny);
    atomicAdd(&vn[3 * i2 + 2], nz);
}

// ---- Normalize (LDS-staged, coalesced). ----
__global__ void vn_normalize(float* __restrict__ vn, int n_verts) {
    __shared__ float s[3 * 256];
    int base = blockIdx.x * 256 * 3;
    int total = n_verts * 3;

    #pragma unroll
    for (int k = 0; k < 3; ++k) {
        int idx = base + k * 256 + threadIdx.x;
        if (idx < total) s[k * 256 + threadIdx.x] = vn[idx];
    }
    __syncthreads();

    int vtx = blockIdx.x * 256 + threadIdx.x;
    if (vtx < n_verts) {
        float x = s[3 * threadIdx.x + 0];
        float y = s[3 * threadIdx.x + 1];
        float z = s[3 * threadIdx.x + 2];
        float norm = sqrtf(x * x + y * y + z * z);
        float inv = 1.0f / fmaxf(norm, VN_EPS);
        s[3 * threadIdx.x + 0] = x * inv;
        s[3 * threadIdx.x + 1] = y * inv;
        s[3 * threadIdx.x + 2] = z * inv;
    }
    __syncthreads();

    #pragma unroll
    for (int k = 0; k < 3; ++k) {
        int idx = base + k * 256 + threadIdx.x;
        if (idx < total) vn[idx] = s[k * 256 + threadIdx.x];
    }
}

extern "C" void kernel_launch(void* const* d_in, const int* in_sizes, int n_in,
                              void* d_out, int out_size, void* d_ws, size_t ws_size,
                              hipStream_t stream) {
    const float* v = (const float*)d_in[0];
    const int* faces = (const int*)d_in[1];
    float* vn = (float*)d_out;

    int n_verts = in_sizes[0] / 3;
    int n_faces = in_sizes[1] / 3;
    int block = 256;

    hipMemsetAsync(vn, 0, (size_t)out_size * sizeof(float), stream);

    size_t fn_bytes = (size_t)3 * n_faces * sizeof(float);
    size_t need_full = 4096 + fn_bytes;
    int n_chunks = (n_faces + CHUNK_FACES - 1) / CHUNK_FACES;
    int vps = (n_verts + 7) / 8;
    int grid_f = (n_faces + block - 1) / block;
    int grid_v = (n_verts + block - 1) / block;
    int grid_q = 2048;  // 256 CU x 8 blocks; low-VGPR kernel, fills the machine

    if (ws_size >= need_full) {
        int* counters = (int*)d_ws;
        float* fn = (float*)((char*)d_ws + 4096);
        hipMemsetAsync(counters, 0, 64, stream);
        vn_face_normals<<<grid_f, block, 0, stream>>>(v, faces, fn, n_faces);
        vn_scatter_fn<<<grid_q, block, 0, stream>>>(faces, fn, vn, counters,
                                                    n_faces, n_chunks, vps);
    } else if (ws_size >= 64) {
        int* counters = (int*)d_ws;
        hipMemsetAsync(counters, 0, 64, stream);
        vn_scatter_recompute<<<grid_q, block, 0, stream>>>(v, faces, vn, counters,
                                                           n_faces, n_chunks, vps);
    } else {
        vn_face_scatter<<<grid_f, block, 0, stream>>>(v, faces, vn, n_faces);
    }

    vn_normalize<<<grid_v, block, 0, stream>>>(vn, n_verts);
}